// Round 12
// baseline (135.076 us; speedup 1.0000x reference)
//
#include <hip/hip_runtime.h>

#define CIN   128
#define HH    224
#define WW    224
#define COUT  256
#define HO    222
#define WO    222
#define HWSZ  (224 * 224)
#define PLANE (224 * 224 * 64)   // one channel-half plane of packed x, in elems

typedef unsigned short u16;
typedef unsigned int   u32;
typedef __bf16  bf16x8 __attribute__((ext_vector_type(8)));
typedef float   f32x16 __attribute__((ext_vector_type(16)));

__device__ __forceinline__ u16 f2bf(float f) {
  union { float f; u32 u; } v; v.f = f;
  u32 u = v.u;
  return (u16)((u + 0x7FFFu + ((u >> 16) & 1u)) >> 16);  // RNE
}

// ---------------- pre-pass (round-5 proven version, unchanged) ----------------
// blocks 0..447: pack x -> xp [ch(2)][h(224)][w(224)][jc'(8)][e(8)] bf16,
//   granule jc' holds c-block jc'^(w&7); write-side transpose tileT[w][c].
// blocks 448..591: pack w -> wp [mt(2)][kh(3)][ch(2)][kw(3)][mr(128)][jc'(8)][e(8)],
//   granule jc' holds c-block jc'^(mr&7).
__global__ void prep(const float* __restrict__ x, const float* __restrict__ w,
                     u16* __restrict__ xp, u16* __restrict__ wp) {
  const int t = threadIdx.x;
  if (blockIdx.x < 448) {
    const int h  = blockIdx.x >> 1;
    const int ch = blockIdx.x & 1;
    __shared__ u16 tileT[224][72];              // 32,256 B
#pragma unroll
    for (int i = 0; i < 14; ++i) {              // 64 c-rows * 56 float4
      int idx = i * 256 + t;
      int c   = idx / 56;
      int wq  = idx % 56;
      float4 v = *(const float4*)(&x[(size_t)(ch * 64 + c) * HWSZ + h * WW + wq * 4]);
      tileT[wq * 4 + 0][c] = f2bf(v.x);
      tileT[wq * 4 + 1][c] = f2bf(v.y);
      tileT[wq * 4 + 2][c] = f2bf(v.z);
      tileT[wq * 4 + 3][c] = f2bf(v.w);
    }
    __syncthreads();
#pragma unroll
    for (int i = 0; i < 7; ++i) {               // 224 w * 8 granules
      int idx  = i * 256 + t;
      int ww   = idx >> 3;
      int jcp  = idx & 7;
      int jsrc = (jcp ^ (ww & 7)) * 8;          // contiguous 8 u16 -> b128
      uint4 v = *(const uint4*)(&tileT[ww][jsrc]);
      *(uint4*)(&xp[(size_t)ch * PLANE + (size_t)(h * WW + ww) * 64 + jcp * 8]) = v;
    }
  } else {
    int u    = (blockIdx.x - 448) * 256 + t;    // 0..36863 (16B granules of wp)
    int jcp  = u & 7;
    int mr   = (u >> 3) & 127;
    int rest = u >> 10;                         // ((mt*3+kh)*2+ch)*3+kw
    int kw   = rest % 3;
    int q    = rest / 3;
    int ch   = q & 1;
    int r    = q >> 1;
    int kh   = r % 3;
    int mt   = r / 3;
    int oc   = mt * 128 + mr;
    int cb   = ch * 64 + (jcp ^ (mr & 7)) * 8;
    u16 o[8];
#pragma unroll
    for (int e = 0; e < 8; ++e)
      o[e] = f2bf(w[((size_t)(oc * CIN + cb + e) * 3 + kh) * 3 + kw]);
    uint4 v;
    v.x = (u32)o[0] | ((u32)o[1] << 16);
    v.y = (u32)o[2] | ((u32)o[3] << 16);
    v.z = (u32)o[4] | ((u32)o[5] << 16);
    v.w = (u32)o[6] | ((u32)o[7] << 16);
    *(uint4*)(&wp[(size_t)u * 8]) = v;
  }
}

// ---------------- async global->LDS, 16B per lane ----------------
__device__ __forceinline__ void lds_dma16(const u16* g, u16* l) {
  __builtin_amdgcn_global_load_lds(
      reinterpret_cast<__attribute__((address_space(1))) u32*>(
          reinterpret_cast<uintptr_t>(g)),
      reinterpret_cast<__attribute__((address_space(3))) u32*>(
          reinterpret_cast<uintptr_t>(l)),
      16, 0, 0);
}

// ---------------- main: 32x32x16 MFMA variant (instruction-tax probe) -------
// 8 schedule/locality/occupancy variants all landed at conv ~42us (floor 14);
// the untouched axis is MFMA shape. 32x32x16 at a 64x64 wave tile (2x2 frags):
// per (kw,ks) group 2 A + 2 B b128 loads feed 4 MFMAs -> ~43% fewer LDS reads
// per FLOP, ~45% fewer instructions/round, higher MFMA ceiling (2495 vs 2075).
// If the invariant stall is per-instruction latency tax, this cuts it.
// Operand layout (analog of our verified 16x16 usage): A row = lane&31,
// k = (lane>>5)*8+e; B col = lane&31, same k. C/D: col=lane&31,
// row=(reg&3)+8*(reg>>2)+4*(lane>>5) [m74/m101-verified].
// Block M=128 x N=128 (2x2 waves of 64x64); grid 888 = 222 oh x 2 mt x 2 nt,
// XCD-banded; cols >=222 masked (garbage B cols stay column-local in A*B).
// Schedule = R5's proven shape: 2 LDS buffers, stage-next-first, 1 barrier.
__global__ __launch_bounds__(256, 3) void conv_mfma(const u16* __restrict__ wp,
                                                    const u16* __restrict__ xp,
                                                    float* __restrict__ out) {
  __shared__ u16 ldsB[2][10240];   // 2 x 20KB: 160 staged cols x 64 elems

  const int tid  = threadIdx.x;
  const int lane = tid & 63;
  const int wave = tid >> 6;
  const int l31  = lane & 31;
  const int hl   = lane >> 5;      // k-half selector
  const int wm   = wave >> 1;      // wave m-tile 0/1 (64 rows)
  const int wn   = wave & 1;       // wave n-tile 0/1 (64 cols)

  const int bx  = blockIdx.x;
  const int xcd = bx & 7;
  const int u   = xcd * 111 + (bx >> 3);  // 0..887, XCD-banded (888%8==0)
  const int oh  = u >> 2;                 // 0..221
  const int mt  = (u >> 1) & 1;
  const int nt  = u & 1;

  f32x16 acc[2][2];
#pragma unroll
  for (int i = 0; i < 2; ++i)
#pragma unroll
    for (int j = 0; j < 2; ++j)
#pragma unroll
      for (int r = 0; r < 16; ++r) acc[i][j][r] = 0.f;

  // A granule swizzle per ks: c-block = ks*2+hl, granule = cblock^(mr&7),
  // mr&7 == lane&7 (wm*64, i*32 are 0 mod 8).
  int swA[4];
#pragma unroll
  for (int ks = 0; ks < 4; ++ks)
    swA[ks] = ((ks * 2 + hl) ^ (lane & 7)) << 3;
  int rowA[2];
#pragma unroll
  for (int i = 0; i < 2; ++i)
    rowA[i] = (wm * 64 + i * 32 + l31) * 64;

  // prologue: stage round 0 (ch=0, kh=0) into buffer 0; 20 x 1KB units
  {
    const u16* g0 = xp + (size_t)oh * (WW * 64) + nt * (128 * 64);
#pragma unroll
    for (int uu = 0; uu < 5; ++uu) {
      const int unit = wave * 5 + uu;
      lds_dma16(g0 + unit * 512 + lane * 8, &ldsB[0][unit * 512]);
    }
  }
  __syncthreads();               // drain -> buf0 valid

#pragma unroll 1
  for (int s = 0; s < 6; ++s) {
    const int cur = s & 1;

    // issue NEXT round's staging first; latency hides under this round's MFMAs
    if (s < 5) {
      const int sn  = s + 1;
      const u16* gn = xp + (size_t)(sn & 1) * PLANE +
                      (size_t)(oh + (sn >> 1)) * (WW * 64) + nt * (128 * 64);
      u16* dst = &ldsB[cur ^ 1][0];
#pragma unroll
      for (int uu = 0; uu < 5; ++uu) {
        const int unit = wave * 5 + uu;
        lds_dma16(gn + unit * 512 + lane * 8, dst + unit * 512);
      }
    }

    const int ch = s & 1;
    const int kh = s >> 1;

    const u16* Ab = wp + (size_t)((mt * 3 + kh) * 2 + ch) * 24576;
    const u16* Bb = &ldsB[cur][0];

#pragma unroll
    for (int kw = 0; kw < 3; ++kw) {
      const int scol = (l31 + kw) & 7;           // B col&7 (wn*64,j*32 are 0 mod 8)
      const int cbas = (wn * 64 + l31 + kw) * 64;
#pragma unroll
      for (int ks = 0; ks < 4; ++ks) {
        const int swB = ((ks * 2 + hl) ^ scol) << 3;
        bf16x8 af[2], bg[2];
#pragma unroll
        for (int i = 0; i < 2; ++i)
          af[i] = *reinterpret_cast<const bf16x8*>(Ab + kw * 8192 + rowA[i] + swA[ks]);
#pragma unroll
        for (int j = 0; j < 2; ++j)
          bg[j] = *reinterpret_cast<const bf16x8*>(Bb + cbas + j * 2048 + swB);
#pragma unroll
        for (int i = 0; i < 2; ++i)
#pragma unroll
          for (int j = 0; j < 2; ++j)
            acc[i][j] = __builtin_amdgcn_mfma_f32_32x32x16_bf16(af[i], bg[j],
                                                                acc[i][j], 0, 0, 0);
      }
    }

    __syncthreads();   // vmcnt(0) drains staging (issued a full round ago) + barrier
  }

  // epilogue: 32x32 C/D map col=lane&31, row=(reg&3)+8*(reg>>2)+4*hl (m74/m101)
  const int mb = mt * 128 + wm * 64;
#pragma unroll
  for (int i = 0; i < 2; ++i) {
#pragma unroll
    for (int j = 0; j < 2; ++j) {
      const int col = nt * 128 + wn * 64 + j * 32 + l31;
      if (col < WO) {
        float* op = out + (size_t)oh * WO + col;
#pragma unroll
        for (int r = 0; r < 16; ++r) {
          const int row = mb + i * 32 + (r & 3) + 8 * (r >> 2) + 4 * hl;
          op[(size_t)row * (HO * WO)] = acc[i][j][r];
        }
      }
    }
  }
}

// ---------------- fallback (ws too small): naive fp32 direct conv ----------------
__global__ void conv_naive(const float* __restrict__ x, const float* __restrict__ w,
                           float* __restrict__ out) {
  int idx = blockIdx.x * 256 + threadIdx.x;
  if (idx >= COUT * HO * WO) return;
  int ow  = idx % WO;
  int tmp = idx / WO;
  int oh  = tmp % HO;
  int oc  = tmp / HO;
  float s = 0.f;
  for (int c = 0; c < CIN; ++c)
    for (int kh = 0; kh < 3; ++kh) {
      const float* xr = &x[(size_t)(c * HH + oh + kh) * WW + ow];
      const float* wr = &w[((size_t)(oc * CIN + c) * 3 + kh) * 3];
      s += xr[0] * wr[0] + xr[1] * wr[1] + xr[2] * wr[2];
    }
  out[idx] = s;
}

extern "C" void kernel_launch(void* const* d_in, const int* in_sizes, int n_in,
                              void* d_out, int out_size, void* d_ws, size_t ws_size,
                              hipStream_t stream) {
  const float* x    = (const float*)d_in[0];
  const float* kern = (const float*)d_in[1];
  float* out        = (float*)d_out;

  const size_t WP_BYTES = (size_t)36864 * 16;        // 589,824
  const size_t XP_BYTES = (size_t)2 * PLANE * 2;     // 12,845,056
  const size_t SLACK    = 65536;                     // staging halo tail reads

  if (ws_size >= WP_BYTES + XP_BYTES + SLACK) {
    u16* wp = (u16*)d_ws;
    u16* xp = (u16*)((char*)d_ws + WP_BYTES);
    hipLaunchKernelGGL(prep, dim3(592), dim3(256), 0, stream, x, kern, xp, wp);
    hipLaunchKernelGGL(conv_mfma, dim3(888), dim3(256), 0, stream, wp, xp, out);
  } else {
    int total = COUT * HO * WO;
    hipLaunchKernelGGL(conv_naive, dim3((total + 255) / 256), dim3(256), 0, stream,
                       x, kern, out);
  }
}

// Round 13
// 112.105 us; speedup vs baseline: 1.2049x; 1.2049x over previous
//
#include <hip/hip_runtime.h>

#define CIN   128
#define HH    224
#define WW    224
#define COUT  256
#define HO    222
#define WO    222
#define HWSZ  (224 * 224)
#define PLANE (224 * 224 * 64)   // one channel-half plane of packed x, in elems

typedef unsigned short u16;
typedef unsigned int   u32;
typedef __bf16  bf16x8 __attribute__((ext_vector_type(8)));
typedef float   f32x4  __attribute__((ext_vector_type(4)));

__device__ __forceinline__ u16 f2bf(float f) {
  union { float f; u32 u; } v; v.f = f;
  u32 u = v.u;
  return (u16)((u + 0x7FFFu + ((u >> 16) & 1u)) >> 16);  // RNE
}

// ---------------- pre-pass (write-side transpose — round-5 best) ----------------
// blocks 0..447: pack x -> xp [ch(2)][h(224)][w(224)][jc'(8)][e(8)] bf16,
//   granule jc' holds c-block jc'^(w&7). Transpose on the WRITE side:
//   tileT[w][c] (row stride 72 u16 = 144B). Phase 1: coalesced float4 loads +
//   4 scalar ds_write_u16 (224 wave-ops). Phase 2: granule = 8 contiguous u16
//   -> one aligned ds_read_b128 (28 wave-ops/block).
// blocks 448..591: pack w -> wp [mt(2)][kh(3)][ch(2)][kw(3)][mr(128)][jc'(8)][e(8)],
//   granule jc' holds c-block jc'^(mr&7).
__global__ void prep(const float* __restrict__ x, const float* __restrict__ w,
                     u16* __restrict__ xp, u16* __restrict__ wp) {
  const int t = threadIdx.x;
  if (blockIdx.x < 448) {
    const int h  = blockIdx.x >> 1;
    const int ch = blockIdx.x & 1;
    __shared__ u16 tileT[224][72];              // 32,256 B
#pragma unroll
    for (int i = 0; i < 14; ++i) {              // 64 c-rows * 56 float4
      int idx = i * 256 + t;
      int c   = idx / 56;
      int wq  = idx % 56;
      float4 v = *(const float4*)(&x[(size_t)(ch * 64 + c) * HWSZ + h * WW + wq * 4]);
      tileT[wq * 4 + 0][c] = f2bf(v.x);
      tileT[wq * 4 + 1][c] = f2bf(v.y);
      tileT[wq * 4 + 2][c] = f2bf(v.z);
      tileT[wq * 4 + 3][c] = f2bf(v.w);
    }
    __syncthreads();
#pragma unroll
    for (int i = 0; i < 7; ++i) {               // 224 w * 8 granules
      int idx  = i * 256 + t;
      int ww   = idx >> 3;
      int jcp  = idx & 7;
      int jsrc = (jcp ^ (ww & 7)) * 8;          // contiguous 8 u16 -> b128
      uint4 v = *(const uint4*)(&tileT[ww][jsrc]);
      *(uint4*)(&xp[(size_t)ch * PLANE + (size_t)(h * WW + ww) * 64 + jcp * 8]) = v;
    }
  } else {
    int u    = (blockIdx.x - 448) * 256 + t;    // 0..36863 (16B granules of wp)
    int jcp  = u & 7;
    int mr   = (u >> 3) & 127;
    int rest = u >> 10;                         // ((mt*3+kh)*2+ch)*3+kw
    int kw   = rest % 3;
    int q    = rest / 3;
    int ch   = q & 1;
    int r    = q >> 1;
    int kh   = r % 3;
    int mt   = r / 3;
    int oc   = mt * 128 + mr;
    int cb   = ch * 64 + (jcp ^ (mr & 7)) * 8;
    u16 o[8];
#pragma unroll
    for (int e = 0; e < 8; ++e)
      o[e] = f2bf(w[((size_t)(oc * CIN + cb + e) * 3 + kh) * 3 + kw]);
    uint4 v;
    v.x = (u32)o[0] | ((u32)o[1] << 16);
    v.y = (u32)o[2] | ((u32)o[3] << 16);
    v.z = (u32)o[4] | ((u32)o[5] << 16);
    v.w = (u32)o[6] | ((u32)o[7] << 16);
    *(uint4*)(&wp[(size_t)u * 8]) = v;
  }
}

// ---------------- async global->LDS, 16B per lane ----------------
__device__ __forceinline__ void lds_dma16(const u16* g, u16* l) {
  __builtin_amdgcn_global_load_lds(
      reinterpret_cast<__attribute__((address_space(1))) u32*>(
          reinterpret_cast<uintptr_t>(g)),
      reinterpret_cast<__attribute__((address_space(3))) u32*>(
          reinterpret_cast<uintptr_t>(l)),
      16, 0, 0);
}

// ---------------- main: half-row implicit-GEMM conv (best measured: R5) -----
// grid 888 = 222 oh x 2 mt x 2 nt, XCD-banded u=(bx&7)*111+(bx>>3).
// Block tile M=128 x N=112; 4 waves split M; acc[2][7]; 4 blocks/CU.
// B double-buffered in LDS; next round's DMAs issued before compute; one
// __syncthreads per round.
// Session A/B ledger (conv dispatch ~42us in every healthy config):
//   barrier restructure null (R1); occupancy 2x/3x/4x null (R3/R7/R8);
//   64x64 tile reg-starved (R6: VGPR 60, Mfma 27.5%, all pipes <30%);
//   A-panel hoist null (R7); XCD-banded producer + wp x8 regressed (R9);
//   fused staging regressed (R10: FETCH up, scratch); counted-vmcnt 3-buf
//   deep pipeline null (R11); 32x32x16 shape regressed (R12: bank conflicts
//   + reg cap). Conv is latency-bound ~3x above its 14us MFMA floor,
//   invariant to every HIP-source-level axis tried over 12 rounds.
__global__ __launch_bounds__(256, 4) void conv_mfma(const u16* __restrict__ wp,
                                                    const u16* __restrict__ xp,
                                                    float* __restrict__ out) {
  __shared__ u16 ldsB[2][8192];    // 2 x 16KB: 128 staged cols x 64 elems

  const int tid  = threadIdx.x;
  const int lane = tid & 63;
  const int wave = tid >> 6;
  const int quad = lane >> 4;
  const int lr   = lane & 15;

  const int bx  = blockIdx.x;
  const int xcd = bx & 7;
  const int u   = xcd * 111 + (bx >> 3);  // 0..887, XCD-banded
  const int oh  = u >> 2;                 // 0..221
  const int mt  = (u >> 1) & 1;
  const int nt  = u & 1;

  f32x4 acc[2][7];
#pragma unroll
  for (int i = 0; i < 2; ++i)
#pragma unroll
    for (int j = 0; j < 7; ++j) acc[i][j] = {0.f, 0.f, 0.f, 0.f};

  int swA[2];
#pragma unroll
  for (int ks = 0; ks < 2; ++ks)
    swA[ks] = ((ks * 4 + quad) ^ (lr & 7)) << 3;

  // prologue: stage round 0 (ch=0, kh=0) into buffer 0
  {
    const u16* g0 = xp + (size_t)oh * (WW * 64) + nt * (112 * 64);
#pragma unroll
    for (int uu = 0; uu < 4; ++uu) {
      const int unit = wave * 4 + uu;          // 16 x 1KB units = 128 cols
      lds_dma16(g0 + unit * 512 + lane * 8, &ldsB[0][unit * 512]);
    }
  }
  __syncthreads();               // drain -> buf0 valid

#pragma unroll 1
  for (int s = 0; s < 6; ++s) {
    const int cur = s & 1;

    // issue NEXT round's staging first; latency hides under this round's MFMAs
    if (s < 5) {
      const int sn  = s + 1;
      const u16* gn = xp + (size_t)(sn & 1) * PLANE +
                      (size_t)(oh + (sn >> 1)) * (WW * 64) + nt * (112 * 64);
      u16* dst = &ldsB[cur ^ 1][0];
#pragma unroll
      for (int uu = 0; uu < 4; ++uu) {
        const int unit = wave * 4 + uu;
        lds_dma16(gn + unit * 512 + lane * 8, dst + unit * 512);
      }
    }

    const int ch = s & 1;
    const int kh = s >> 1;

    // per-lane A base: wp [mt][kh][ch][kw][mr(128)][jc'(8)][e(8)], L2/L3-resident
    const u16* Ab = wp + (size_t)((mt * 3 + kh) * 2 + ch) * 24576 +
                    wave * 2048 + lr * 64;
    const u16* Bb = &ldsB[cur][0];

#pragma unroll
    for (int kw = 0; kw < 3; ++kw) {
      const int bq  = (lr + kw) * 64;          // local col offset (j adds 16 cols)
      const int sw7 = (lr + kw) & 7;
#pragma unroll
      for (int ks = 0; ks < 2; ++ks) {
        const int swB = ((ks * 4 + quad) ^ sw7) << 3;
        bf16x8 af[2], bg[7];
#pragma unroll
        for (int i = 0; i < 2; ++i)
          af[i] = *reinterpret_cast<const bf16x8*>(Ab + kw * 8192 + i * 1024 + swA[ks]);
#pragma unroll
        for (int j = 0; j < 7; ++j)
          bg[j] = *reinterpret_cast<const bf16x8*>(Bb + bq + j * 1024 + swB);
#pragma unroll
        for (int i = 0; i < 2; ++i)
#pragma unroll
          for (int j = 0; j < 7; ++j)
            acc[i][j] = __builtin_amdgcn_mfma_f32_16x16x32_bf16(af[i], bg[j], acc[i][j], 0, 0, 0);
      }
    }

    __syncthreads();   // per-wave vmcnt(0) (DMAs issued a full round ago) + barrier
  }

  // epilogue: C/D map col=lane&15, row=quad*4+reg (m89/m91); mask cols >= 222
  const int mb = mt * 128 + wave * 32;
#pragma unroll
  for (int i = 0; i < 2; ++i) {
#pragma unroll
    for (int j = 0; j < 7; ++j) {
      const int col = nt * 112 + j * 16 + lr;
      if (col < WO) {
        float* op = out + (size_t)(mb + i * 16 + quad * 4) * (HO * WO) +
                    (size_t)oh * WO + col;
#pragma unroll
        for (int r = 0; r < 4; ++r)
          op[(size_t)r * (HO * WO)] = acc[i][j][r];
      }
    }
  }
}

// ---------------- fallback (ws too small): naive fp32 direct conv ----------------
__global__ void conv_naive(const float* __restrict__ x, const float* __restrict__ w,
                           float* __restrict__ out) {
  int idx = blockIdx.x * 256 + threadIdx.x;
  if (idx >= COUT * HO * WO) return;
  int ow  = idx % WO;
  int tmp = idx / WO;
  int oh  = tmp % HO;
  int oc  = tmp / HO;
  float s = 0.f;
  for (int c = 0; c < CIN; ++c)
    for (int kh = 0; kh < 3; ++kh) {
      const float* xr = &x[(size_t)(c * HH + oh + kh) * WW + ow];
      const float* wr = &w[((size_t)(oc * CIN + c) * 3 + kh) * 3];
      s += xr[0] * wr[0] + xr[1] * wr[1] + xr[2] * wr[2];
    }
  out[idx] = s;
}

extern "C" void kernel_launch(void* const* d_in, const int* in_sizes, int n_in,
                              void* d_out, int out_size, void* d_ws, size_t ws_size,
                              hipStream_t stream) {
  const float* x    = (const float*)d_in[0];
  const float* kern = (const float*)d_in[1];
  float* out        = (float*)d_out;

  const size_t WP_BYTES = (size_t)36864 * 16;        // 589,824
  const size_t XP_BYTES = (size_t)2 * PLANE * 2;     // 12,845,056

  if (ws_size >= WP_BYTES + XP_BYTES) {
    u16* wp = (u16*)d_ws;
    u16* xp = (u16*)((char*)d_ws + WP_BYTES);
    hipLaunchKernelGGL(prep, dim3(592), dim3(256), 0, stream, x, kern, xp, wp);
    hipLaunchKernelGGL(conv_mfma, dim3(888), dim3(256), 0, stream, wp, xp, out);
  } else {
    int total = COUT * HO * WO;
    hipLaunchKernelGGL(conv_naive, dim3((total + 255) / 256), dim3(256), 0, stream,
                       x, kern, out);
  }
}